// Round 1
// baseline (1817.538 us; speedup 1.0000x reference)
//
#include <hip/hip_runtime.h>
#include <math.h>

#define HID 64
#define HEADS 4
#define HDIM 16
#define N_MOL 2048
#define N_PROT 4096
#define E_MOL 32768
#define E_PROT 131072
#define BATCH 32

// ---------------------------------------------------------------------------
// Node input linear: mol 11->64, prot 15->64. One wave per node.
__global__ void k_node_lin(const float* __restrict__ mol_x, const float* __restrict__ prot_x,
                           const float* __restrict__ Wm, const float* __restrict__ bm,
                           const float* __restrict__ Wp, const float* __restrict__ bp,
                           float* __restrict__ xm, float* __restrict__ xp) {
    int blk = blockIdx.x, t = threadIdx.x;
    if (blk < N_MOL) {
        const float* xr = mol_x + blk * 11;
        float acc = bm[t];
#pragma unroll
        for (int i = 0; i < 11; ++i) acc += xr[i] * Wm[i * HID + t];
        xm[blk * HID + t] = acc;
    } else {
        int n = blk - N_MOL;
        const float* xr = prot_x + n * 15;
        float acc = bp[t];
#pragma unroll
        for (int i = 0; i < 15; ++i) acc += xr[i] * Wp[i * HID + t];
        xp[n * HID + t] = acc;
    }
}

// ---------------------------------------------------------------------------
// Fused edge-linear + message + scatter-add. 4 edges per 256-thread block.
// em is layer-invariant, so we recompute 10->64 on the fly (reads 10 floats
// instead of 64 from HBM).
__global__ void k_scatter(const float* __restrict__ xm, const float* __restrict__ xp,
                          const float* __restrict__ mol_ea, const float* __restrict__ prot_ea,
                          const int* __restrict__ mol_ei, const int* __restrict__ prot_ei,
                          const float* __restrict__ Wem, const float* __restrict__ bem,
                          const float* __restrict__ Wep, const float* __restrict__ bep,
                          float* __restrict__ aggm, float* __restrict__ aggp) {
    int t = threadIdx.x & 63;
    int sub = threadIdx.x >> 6;
    int blk = blockIdx.x;
    if (blk < E_MOL / 4) {
        int e = blk * 4 + sub;
        int src = mol_ei[e], dst = mol_ei[E_MOL + e];
        const float* ea = mol_ea + e * 10;
        float acc = bem[t];
#pragma unroll
        for (int i = 0; i < 10; ++i) acc += ea[i] * Wem[i * HID + t];
        float v = fmaxf(acc + xm[src * HID + t], 0.f);
        unsafeAtomicAdd(&aggm[dst * HID + t], v);
    } else {
        int e = (blk - E_MOL / 4) * 4 + sub;
        int src = prot_ei[e], dst = prot_ei[E_PROT + e];
        const float* ea = prot_ea + e * 10;
        float acc = bep[t];
#pragma unroll
        for (int i = 0; i < 10; ++i) acc += ea[i] * Wep[i * HID + t];
        float v = fmaxf(acc + xp[src * HID + t], 0.f);
        unsafeAtomicAdd(&aggp[dst * HID + t], v);
    }
}

// ---------------------------------------------------------------------------
// GINE node update: h=x+agg; x_new=relu(relu(h@W1+b1)@W2+b2). One wave/node.
__global__ void k_update(float* __restrict__ xm, float* __restrict__ xp,
                         const float* __restrict__ aggm, const float* __restrict__ aggp,
                         const float* __restrict__ W1m, const float* __restrict__ b1m,
                         const float* __restrict__ W2m, const float* __restrict__ b2m,
                         const float* __restrict__ W1p, const float* __restrict__ b1p,
                         const float* __restrict__ W2p, const float* __restrict__ b2p) {
    __shared__ float h0[HID];
    __shared__ float h1[HID];
    int t = threadIdx.x;
    float* x;
    const float *agg, *W1, *b1, *W2, *b2;
    int n;
    if (blockIdx.x < N_MOL) {
        n = blockIdx.x; x = xm; agg = aggm; W1 = W1m; b1 = b1m; W2 = W2m; b2 = b2m;
    } else {
        n = blockIdx.x - N_MOL; x = xp; agg = aggp; W1 = W1p; b1 = b1p; W2 = W2p; b2 = b2p;
    }
    h0[t] = x[n * HID + t] + agg[n * HID + t];
    __syncthreads();
    float acc = b1[t];
#pragma unroll 8
    for (int k = 0; k < HID; ++k) acc += h0[k] * W1[k * HID + t];
    h1[t] = fmaxf(acc, 0.f);
    __syncthreads();
    float acc2 = b2[t];
#pragma unroll 8
    for (int k = 0; k < HID; ++k) acc2 += h1[k] * W2[k * HID + t];
    x[n * HID + t] = fmaxf(acc2, 0.f);
}

// ---------------------------------------------------------------------------
// QKV projections for both attention directions (6 fused 64->64 linears).
__global__ void k_qkv(const float* __restrict__ xm, const float* __restrict__ xp,
                      const float* __restrict__ mpW, const float* __restrict__ mpb,
                      const float* __restrict__ pmW, const float* __restrict__ pmb,
                      float* __restrict__ Qm, float* __restrict__ Kp, float* __restrict__ Vp,
                      float* __restrict__ Qp, float* __restrict__ Km, float* __restrict__ Vm) {
    __shared__ float row[HID];
    int t = threadIdx.x;
    int b = blockIdx.x;
    const float *src, *W, *bias;
    float* dst;
    int n;
    if (b < 2048)       { n = b;         src = xm; W = mpW;        bias = mpb;       dst = Qm; }
    else if (b < 6144)  { n = b - 2048;  src = xp; W = mpW + 4096; bias = mpb + 64;  dst = Kp; }
    else if (b < 10240) { n = b - 6144;  src = xp; W = mpW + 8192; bias = mpb + 128; dst = Vp; }
    else if (b < 14336) { n = b - 10240; src = xp; W = pmW;        bias = pmb;       dst = Qp; }
    else if (b < 16384) { n = b - 14336; src = xm; W = pmW + 4096; bias = pmb + 64;  dst = Km; }
    else                { n = b - 16384; src = xm; W = pmW + 8192; bias = pmb + 128; dst = Vm; }
    row[t] = src[n * HID + t];
    __syncthreads();
    float acc = bias[t];
#pragma unroll 8
    for (int k = 0; k < HID; ++k) acc += row[k] * W[k * HID + t];
    dst[n * HID + t] = acc;
}

// ---------------------------------------------------------------------------
// Cross attention, online softmax. One block (4 waves) per query; wave = head;
// lanes parallel over keys; butterfly merge of (m,l,acc[16]) across the wave.
__global__ __launch_bounds__(256) void k_attn(
    const float* __restrict__ Qm, const float* __restrict__ Kp, const float* __restrict__ Vp,
    const float* __restrict__ Qp, const float* __restrict__ Km, const float* __restrict__ Vm,
    const float* __restrict__ xm, const float* __restrict__ xp,
    float* __restrict__ Hm, float* __restrict__ Hp) {
    __shared__ float qrow[HID];
    __shared__ float outrow[HID];
    int tid = threadIdx.x;
    int w = tid >> 6, lane = tid & 63;
    const float *Q, *K, *V, *X;
    float* H;
    int nq, Nk;
    if (blockIdx.x < N_MOL) {
        nq = blockIdx.x; Q = Qm; K = Kp; V = Vp; X = xm; H = Hm; Nk = N_PROT;
    } else {
        nq = blockIdx.x - N_MOL; Q = Qp; K = Km; V = Vm; X = xp; H = Hp; Nk = N_MOL;
    }
    if (tid < HID) qrow[tid] = Q[nq * HID + tid];
    __syncthreads();
    float q[HDIM];
#pragma unroll
    for (int d = 0; d < HDIM; ++d) q[d] = qrow[w * HDIM + d] * 0.25f;  // fold 1/sqrt(16)
    float m = -INFINITY, l = 0.f;
    float acc[HDIM];
#pragma unroll
    for (int d = 0; d < HDIM; ++d) acc[d] = 0.f;
    for (int k = lane; k < Nk; k += 64) {
        const float* kr = K + k * HID + w * HDIM;
        float s = 0.f;
#pragma unroll
        for (int d = 0; d < HDIM; ++d) s += q[d] * kr[d];
        float mn = fmaxf(m, s);
        float alpha = __expf(m - mn);
        float p = __expf(s - mn);
        const float* vr = V + k * HID + w * HDIM;
        l = l * alpha + p;
#pragma unroll
        for (int d = 0; d < HDIM; ++d) acc[d] = acc[d] * alpha + p * vr[d];
        m = mn;
    }
#pragma unroll
    for (int off = 32; off > 0; off >>= 1) {
        float m2 = __shfl_xor(m, off, 64);
        float l2 = __shfl_xor(l, off, 64);
        float mn = fmaxf(m, m2);
        float a1 = __expf(m - mn), a2 = __expf(m2 - mn);
        l = l * a1 + l2 * a2;
#pragma unroll
        for (int d = 0; d < HDIM; ++d) {
            float o2 = __shfl_xor(acc[d], off, 64);
            acc[d] = acc[d] * a1 + o2 * a2;
        }
        m = mn;
    }
    if (lane == 0) {
        float inv = 1.f / l;
#pragma unroll
        for (int d = 0; d < HDIM; ++d) outrow[w * HDIM + d] = acc[d] * inv;
    }
    __syncthreads();
    if (tid < HID) H[nq * HID + tid] = X[nq * HID + tid] + outrow[tid];
}

// ---------------------------------------------------------------------------
// Per-batch mean-pool (sums + counts via atomics).
__global__ void k_pool(const float* __restrict__ Hm, const float* __restrict__ Hp,
                       const int* __restrict__ mb, const int* __restrict__ pb,
                       float* __restrict__ pool, float* __restrict__ cnt) {
    int t = threadIdx.x, n = blockIdx.x;
    if (n < N_MOL) {
        int b = mb[n];
        unsafeAtomicAdd(&pool[b * 128 + t], Hm[n * HID + t]);
        if (t == 0) unsafeAtomicAdd(&cnt[b * 2 + 0], 1.f);
    } else {
        int p = n - N_MOL;
        int b = pb[p];
        unsafeAtomicAdd(&pool[b * 128 + 64 + t], Hp[p * HID + t]);
        if (t == 0) unsafeAtomicAdd(&cnt[b * 2 + 1], 1.f);
    }
}

// ---------------------------------------------------------------------------
// Head: z = [mean_mol | mean_prot]; relu(z@fc1+b1)@fc2+b2 -> sigmoid.
__global__ void k_final(const float* __restrict__ pool, const float* __restrict__ cnt,
                        const float* __restrict__ fc1W, const float* __restrict__ fc1b,
                        const float* __restrict__ fc2W, const float* __restrict__ fc2b,
                        float* __restrict__ out) {
    __shared__ float z[128];
    int b = blockIdx.x, t = threadIdx.x;
    float cm = fmaxf(cnt[b * 2 + 0], 1.f), cp = fmaxf(cnt[b * 2 + 1], 1.f);
    z[t] = pool[b * 128 + t] / cm;
    z[64 + t] = pool[b * 128 + 64 + t] / cp;
    __syncthreads();
    float acc = fc1b[t];
#pragma unroll 8
    for (int k = 0; k < 128; ++k) acc += z[k] * fc1W[k * 64 + t];
    float hv = fmaxf(acc, 0.f);
    float prod = hv * fc2W[t];
#pragma unroll
    for (int off = 32; off > 0; off >>= 1) prod += __shfl_xor(prod, off, 64);
    if (t == 0) out[b] = 1.f / (1.f + __expf(-(prod + fc2b[0])));
}

// ---------------------------------------------------------------------------
extern "C" void kernel_launch(void* const* d_in, const int* in_sizes, int n_in,
                              void* d_out, int out_size, void* d_ws, size_t ws_size,
                              hipStream_t stream) {
    const float* mol_x   = (const float*)d_in[0];
    const float* prot_x  = (const float*)d_in[1];
    const float* mol_ea  = (const float*)d_in[2];
    const float* prot_ea = (const float*)d_in[3];
    const int*   mol_ei  = (const int*)d_in[4];
    const int*   prot_ei = (const int*)d_in[5];
    const int*   mol_b   = (const int*)d_in[6];
    const int*   prot_b  = (const int*)d_in[7];
    const float* nlmW = (const float*)d_in[8];
    const float* nlmb = (const float*)d_in[9];
    const float* nlpW = (const float*)d_in[10];
    const float* nlpb = (const float*)d_in[11];
    const float* elmW = (const float*)d_in[12];
    const float* elmb = (const float*)d_in[13];
    const float* elpW = (const float*)d_in[14];
    const float* elpb = (const float*)d_in[15];
    const float* mcW1 = (const float*)d_in[16];
    const float* mcb1 = (const float*)d_in[17];
    const float* mcW2 = (const float*)d_in[18];
    const float* mcb2 = (const float*)d_in[19];
    const float* pcW1 = (const float*)d_in[20];
    const float* pcb1 = (const float*)d_in[21];
    const float* pcW2 = (const float*)d_in[22];
    const float* pcb2 = (const float*)d_in[23];
    const float* mpW  = (const float*)d_in[24];
    const float* mpb  = (const float*)d_in[25];
    const float* pmW  = (const float*)d_in[26];
    const float* pmb  = (const float*)d_in[27];
    const float* fc1W = (const float*)d_in[28];
    const float* fc1b = (const float*)d_in[29];
    const float* fc2W = (const float*)d_in[30];
    const float* fc2b = (const float*)d_in[31];

    float* ws   = (float*)d_ws;
    float* xm   = ws;                 // 2048*64
    float* xp   = xm + 131072;        // 4096*64
    float* aggm = xp + 262144;        // 2048*64  (aggm+aggp contiguous for one memset)
    float* aggp = aggm + 131072;      // 4096*64
    float* Qm   = aggp + 262144;
    float* Kp   = Qm + 131072;
    float* Vp   = Kp + 262144;
    float* Qp   = Vp + 262144;
    float* Km   = Qp + 262144;
    float* Vm   = Km + 131072;
    float* Hm   = Vm + 131072;
    float* Hp   = Hm + 131072;
    float* pool = Hp + 262144;        // 32*128 (+64 counts, contiguous for one memset)
    float* cnt  = pool + 4096;

    k_node_lin<<<N_MOL + N_PROT, 64, 0, stream>>>(mol_x, prot_x, nlmW, nlmb, nlpW, nlpb, xm, xp);

    for (int l = 0; l < 3; ++l) {
        hipMemsetAsync(aggm, 0, (size_t)(131072 + 262144) * sizeof(float), stream);
        k_scatter<<<(E_MOL + E_PROT) / 4, 256, 0, stream>>>(
            xm, xp, mol_ea, prot_ea, mol_ei, prot_ei, elmW, elmb, elpW, elpb, aggm, aggp);
        k_update<<<N_MOL + N_PROT, 64, 0, stream>>>(
            xm, xp, aggm, aggp,
            mcW1 + l * 4096, mcb1 + l * 64, mcW2 + l * 4096, mcb2 + l * 64,
            pcW1 + l * 4096, pcb1 + l * 64, pcW2 + l * 4096, pcb2 + l * 64);
    }

    k_qkv<<<18432, 64, 0, stream>>>(xm, xp, mpW, mpb, pmW, pmb, Qm, Kp, Vp, Qp, Km, Vm);
    k_attn<<<N_MOL + N_PROT, 256, 0, stream>>>(Qm, Kp, Vp, Qp, Km, Vm, xm, xp, Hm, Hp);

    hipMemsetAsync(pool, 0, (size_t)(4096 + 64) * sizeof(float), stream);
    k_pool<<<N_MOL + N_PROT, 64, 0, stream>>>(Hm, Hp, mol_b, prot_b, pool, cnt);
    k_final<<<BATCH, 64, 0, stream>>>(pool, cnt, fc1W, fc1b, fc2W, fc2b, (float*)d_out);
}

// Round 2
// 584.216 us; speedup vs baseline: 3.1111x; 3.1111x over previous
//
#include <hip/hip_runtime.h>
#include <math.h>

#define HID 64
#define HEADS 4
#define HDIM 16
#define N_MOL 2048
#define N_PROT 4096
#define E_MOL 32768
#define E_PROT 131072
#define BATCH 32

#define TQ 16        // queries per attention block
#define TK 64        // keys per LDS tile
#define KST 68       // padded LDS row stride (words); 68*4=272B keeps 16B align, spreads banks

// ---------------------------------------------------------------------------
// Node input linear: mol 11->64, prot 15->64. One wave per node.
__global__ void k_node_lin(const float* __restrict__ mol_x, const float* __restrict__ prot_x,
                           const float* __restrict__ Wm, const float* __restrict__ bm,
                           const float* __restrict__ Wp, const float* __restrict__ bp,
                           float* __restrict__ xm, float* __restrict__ xp) {
    int blk = blockIdx.x, t = threadIdx.x;
    if (blk < N_MOL) {
        const float* xr = mol_x + blk * 11;
        float acc = bm[t];
#pragma unroll
        for (int i = 0; i < 11; ++i) acc += xr[i] * Wm[i * HID + t];
        xm[blk * HID + t] = acc;
    } else {
        int n = blk - N_MOL;
        const float* xr = prot_x + n * 15;
        float acc = bp[t];
#pragma unroll
        for (int i = 0; i < 15; ++i) acc += xr[i] * Wp[i * HID + t];
        xp[n * HID + t] = acc;
    }
}

// ---------------------------------------------------------------------------
// Fused edge-linear + message + scatter-add. 4 edges per 256-thread block.
__global__ void k_scatter(const float* __restrict__ xm, const float* __restrict__ xp,
                          const float* __restrict__ mol_ea, const float* __restrict__ prot_ea,
                          const int* __restrict__ mol_ei, const int* __restrict__ prot_ei,
                          const float* __restrict__ Wem, const float* __restrict__ bem,
                          const float* __restrict__ Wep, const float* __restrict__ bep,
                          float* __restrict__ aggm, float* __restrict__ aggp) {
    int t = threadIdx.x & 63;
    int sub = threadIdx.x >> 6;
    int blk = blockIdx.x;
    if (blk < E_MOL / 4) {
        int e = blk * 4 + sub;
        int src = mol_ei[e], dst = mol_ei[E_MOL + e];
        const float* ea = mol_ea + e * 10;
        float acc = bem[t];
#pragma unroll
        for (int i = 0; i < 10; ++i) acc += ea[i] * Wem[i * HID + t];
        float v = fmaxf(acc + xm[src * HID + t], 0.f);
        unsafeAtomicAdd(&aggm[dst * HID + t], v);
    } else {
        int e = (blk - E_MOL / 4) * 4 + sub;
        int src = prot_ei[e], dst = prot_ei[E_PROT + e];
        const float* ea = prot_ea + e * 10;
        float acc = bep[t];
#pragma unroll
        for (int i = 0; i < 10; ++i) acc += ea[i] * Wep[i * HID + t];
        float v = fmaxf(acc + xp[src * HID + t], 0.f);
        unsafeAtomicAdd(&aggp[dst * HID + t], v);
    }
}

// ---------------------------------------------------------------------------
// GINE node update: h=x+agg; x_new=relu(relu(h@W1+b1)@W2+b2). One wave/node.
__global__ void k_update(float* __restrict__ xm, float* __restrict__ xp,
                         const float* __restrict__ aggm, const float* __restrict__ aggp,
                         const float* __restrict__ W1m, const float* __restrict__ b1m,
                         const float* __restrict__ W2m, const float* __restrict__ b2m,
                         const float* __restrict__ W1p, const float* __restrict__ b1p,
                         const float* __restrict__ W2p, const float* __restrict__ b2p) {
    __shared__ float h0[HID];
    __shared__ float h1[HID];
    int t = threadIdx.x;
    float* x;
    const float *agg, *W1, *b1, *W2, *b2;
    int n;
    if (blockIdx.x < N_MOL) {
        n = blockIdx.x; x = xm; agg = aggm; W1 = W1m; b1 = b1m; W2 = W2m; b2 = b2m;
    } else {
        n = blockIdx.x - N_MOL; x = xp; agg = aggp; W1 = W1p; b1 = b1p; W2 = W2p; b2 = b2p;
    }
    h0[t] = x[n * HID + t] + agg[n * HID + t];
    __syncthreads();
    float acc = b1[t];
#pragma unroll 8
    for (int k = 0; k < HID; ++k) acc += h0[k] * W1[k * HID + t];
    h1[t] = fmaxf(acc, 0.f);
    __syncthreads();
    float acc2 = b2[t];
#pragma unroll 8
    for (int k = 0; k < HID; ++k) acc2 += h1[k] * W2[k * HID + t];
    x[n * HID + t] = fmaxf(acc2, 0.f);
}

// ---------------------------------------------------------------------------
// QKV projections for both attention directions (6 fused 64->64 linears).
__global__ void k_qkv(const float* __restrict__ xm, const float* __restrict__ xp,
                      const float* __restrict__ mpW, const float* __restrict__ mpb,
                      const float* __restrict__ pmW, const float* __restrict__ pmb,
                      float* __restrict__ Qm, float* __restrict__ Kp, float* __restrict__ Vp,
                      float* __restrict__ Qp, float* __restrict__ Km, float* __restrict__ Vm) {
    __shared__ float row[HID];
    int t = threadIdx.x;
    int b = blockIdx.x;
    const float *src, *W, *bias;
    float* dst;
    int n;
    if (b < 2048)       { n = b;         src = xm; W = mpW;        bias = mpb;       dst = Qm; }
    else if (b < 6144)  { n = b - 2048;  src = xp; W = mpW + 4096; bias = mpb + 64;  dst = Kp; }
    else if (b < 10240) { n = b - 6144;  src = xp; W = mpW + 8192; bias = mpb + 128; dst = Vp; }
    else if (b < 14336) { n = b - 10240; src = xp; W = pmW;        bias = pmb;       dst = Qp; }
    else if (b < 16384) { n = b - 14336; src = xm; W = pmW + 4096; bias = pmb + 64;  dst = Km; }
    else                { n = b - 16384; src = xm; W = pmW + 8192; bias = pmb + 128; dst = Vm; }
    row[t] = src[n * HID + t];
    __syncthreads();
    float acc = bias[t];
#pragma unroll 8
    for (int k = 0; k < HID; ++k) acc += row[k] * W[k * HID + t];
    dst[n * HID + t] = acc;
}

// ---------------------------------------------------------------------------
// Tiled cross attention. Block = TQ queries x 4 heads, 256 threads.
// K/V staged in LDS per 64-key tile (coalesced float4). Each thread owns
// (query-pair, head, key-subset of 8): one K/V row read serves 2 queries.
// Per-thread online softmax; 8-way partial-state merge via shfl_xor.
__global__ __launch_bounds__(256) void k_attn(
    const float* __restrict__ Qm, const float* __restrict__ Kp, const float* __restrict__ Vp,
    const float* __restrict__ Qp, const float* __restrict__ Km, const float* __restrict__ Vm,
    const float* __restrict__ xm, const float* __restrict__ xp,
    float* __restrict__ Hm, float* __restrict__ Hp) {
    __shared__ float Kl[TK * KST];
    __shared__ float Vl[TK * KST];
    __shared__ float outs[TQ * HID];

    int t = threadIdx.x;
    const float *Q, *K, *V, *X;
    float* H;
    int q0, Nk;
    if (blockIdx.x < N_MOL / TQ) {
        q0 = blockIdx.x * TQ;                Q = Qm; K = Kp; V = Vp; X = xm; H = Hm; Nk = N_PROT;
    } else {
        q0 = (blockIdx.x - N_MOL / TQ) * TQ; Q = Qp; K = Km; V = Vm; X = xp; H = Hp; Nk = N_MOL;
    }

    int sub = t & 7;          // key subset: keys sub + 8*i in each tile
    int h   = (t >> 3) & 3;   // head
    int qp  = t >> 5;         // 0..7 -> queries q0+qp and q0+qp+8

    float qa[HDIM], qb[HDIM];
    {
        const float* Qa = Q + (q0 + qp) * HID + h * HDIM;
        const float* Qb = Q + (q0 + qp + 8) * HID + h * HDIM;
#pragma unroll
        for (int d = 0; d < HDIM; ++d) { qa[d] = Qa[d] * 0.25f; qb[d] = Qb[d] * 0.25f; }
    }

    float ma = -INFINITY, la = 0.f, mb = -INFINITY, lb = 0.f;
    float acca[HDIM], accb[HDIM];
#pragma unroll
    for (int d = 0; d < HDIM; ++d) { acca[d] = 0.f; accb[d] = 0.f; }

    for (int kt = 0; kt < Nk; kt += TK) {
        __syncthreads();
        // stage K,V tile (64 rows x 64 floats): 256 threads x 4 float4 each
        const float4* Kg = (const float4*)(K + kt * HID);
        const float4* Vg = (const float4*)(V + kt * HID);
#pragma unroll
        for (int j = 0; j < 4; ++j) {
            int idx = t + j * 256;            // float4 index 0..1023
            int row = idx >> 4, col = (idx & 15) << 2;
            *(float4*)&Kl[row * KST + col] = Kg[idx];
            *(float4*)&Vl[row * KST + col] = Vg[idx];
        }
        __syncthreads();

#pragma unroll 2
        for (int i = 0; i < 8; ++i) {
            int k = sub + 8 * i;
            const float* kr = &Kl[k * KST + h * HDIM];
            const float* vr = &Vl[k * KST + h * HDIM];
            float sa = 0.f, sb = 0.f;
#pragma unroll
            for (int d = 0; d < HDIM; ++d) { sa += qa[d] * kr[d]; sb += qb[d] * kr[d]; }
            float mna = fmaxf(ma, sa);
            float aa = __expf(ma - mna), pa = __expf(sa - mna);
            la = la * aa + pa;
            float mnb = fmaxf(mb, sb);
            float ab = __expf(mb - mnb), pb = __expf(sb - mnb);
            lb = lb * ab + pb;
#pragma unroll
            for (int d = 0; d < HDIM; ++d) {
                float v = vr[d];
                acca[d] = acca[d] * aa + pa * v;
                accb[d] = accb[d] * ab + pb * v;
            }
            ma = mna; mb = mnb;
        }
    }

    // merge 8 partial states (subs = lane bits 0..2)
#pragma unroll
    for (int off = 1; off < 8; off <<= 1) {
        float m2 = __shfl_xor(ma, off, 64);
        float l2 = __shfl_xor(la, off, 64);
        float mn = fmaxf(ma, m2);
        float a1 = __expf(ma - mn), a2 = __expf(m2 - mn);
        la = la * a1 + l2 * a2;
#pragma unroll
        for (int d = 0; d < HDIM; ++d) {
            float o2 = __shfl_xor(acca[d], off, 64);
            acca[d] = acca[d] * a1 + o2 * a2;
        }
        ma = mn;
        m2 = __shfl_xor(mb, off, 64);
        l2 = __shfl_xor(lb, off, 64);
        mn = fmaxf(mb, m2);
        a1 = __expf(mb - mn); a2 = __expf(m2 - mn);
        lb = lb * a1 + l2 * a2;
#pragma unroll
        for (int d = 0; d < HDIM; ++d) {
            float o2 = __shfl_xor(accb[d], off, 64);
            accb[d] = accb[d] * a1 + o2 * a2;
        }
        mb = mn;
    }
    if (sub == 0) {
        float inva = 1.f / la, invb = 1.f / lb;
#pragma unroll
        for (int d = 0; d < HDIM; ++d) {
            outs[qp * HID + h * HDIM + d] = acca[d] * inva;
            outs[(qp + 8) * HID + h * HDIM + d] = accb[d] * invb;
        }
    }
    __syncthreads();
#pragma unroll
    for (int j = 0; j < 4; ++j) {
        int idx = t + j * 256;               // 0..1023 over TQ*HID
        int q = idx >> 6, c = idx & 63;
        H[(q0 + q) * HID + c] = X[(q0 + q) * HID + c] + outs[idx];
    }
}

// ---------------------------------------------------------------------------
// Per-batch mean-pool (sums + counts via atomics).
__global__ void k_pool(const float* __restrict__ Hm, const float* __restrict__ Hp,
                       const int* __restrict__ mb, const int* __restrict__ pb,
                       float* __restrict__ pool, float* __restrict__ cnt) {
    int t = threadIdx.x, n = blockIdx.x;
    if (n < N_MOL) {
        int b = mb[n];
        unsafeAtomicAdd(&pool[b * 128 + t], Hm[n * HID + t]);
        if (t == 0) unsafeAtomicAdd(&cnt[b * 2 + 0], 1.f);
    } else {
        int p = n - N_MOL;
        int b = pb[p];
        unsafeAtomicAdd(&pool[b * 128 + 64 + t], Hp[p * HID + t]);
        if (t == 0) unsafeAtomicAdd(&cnt[b * 2 + 1], 1.f);
    }
}

// ---------------------------------------------------------------------------
// Head: z = [mean_mol | mean_prot]; relu(z@fc1+b1)@fc2+b2 -> sigmoid.
__global__ void k_final(const float* __restrict__ pool, const float* __restrict__ cnt,
                        const float* __restrict__ fc1W, const float* __restrict__ fc1b,
                        const float* __restrict__ fc2W, const float* __restrict__ fc2b,
                        float* __restrict__ out) {
    __shared__ float z[128];
    int b = blockIdx.x, t = threadIdx.x;
    float cm = fmaxf(cnt[b * 2 + 0], 1.f), cp = fmaxf(cnt[b * 2 + 1], 1.f);
    z[t] = pool[b * 128 + t] / cm;
    z[64 + t] = pool[b * 128 + 64 + t] / cp;
    __syncthreads();
    float acc = fc1b[t];
#pragma unroll 8
    for (int k = 0; k < 128; ++k) acc += z[k] * fc1W[k * 64 + t];
    float hv = fmaxf(acc, 0.f);
    float prod = hv * fc2W[t];
#pragma unroll
    for (int off = 32; off > 0; off >>= 1) prod += __shfl_xor(prod, off, 64);
    if (t == 0) out[b] = 1.f / (1.f + __expf(-(prod + fc2b[0])));
}

// ---------------------------------------------------------------------------
extern "C" void kernel_launch(void* const* d_in, const int* in_sizes, int n_in,
                              void* d_out, int out_size, void* d_ws, size_t ws_size,
                              hipStream_t stream) {
    const float* mol_x   = (const float*)d_in[0];
    const float* prot_x  = (const float*)d_in[1];
    const float* mol_ea  = (const float*)d_in[2];
    const float* prot_ea = (const float*)d_in[3];
    const int*   mol_ei  = (const int*)d_in[4];
    const int*   prot_ei = (const int*)d_in[5];
    const int*   mol_b   = (const int*)d_in[6];
    const int*   prot_b  = (const int*)d_in[7];
    const float* nlmW = (const float*)d_in[8];
    const float* nlmb = (const float*)d_in[9];
    const float* nlpW = (const float*)d_in[10];
    const float* nlpb = (const float*)d_in[11];
    const float* elmW = (const float*)d_in[12];
    const float* elmb = (const float*)d_in[13];
    const float* elpW = (const float*)d_in[14];
    const float* elpb = (const float*)d_in[15];
    const float* mcW1 = (const float*)d_in[16];
    const float* mcb1 = (const float*)d_in[17];
    const float* mcW2 = (const float*)d_in[18];
    const float* mcb2 = (const float*)d_in[19];
    const float* pcW1 = (const float*)d_in[20];
    const float* pcb1 = (const float*)d_in[21];
    const float* pcW2 = (const float*)d_in[22];
    const float* pcb2 = (const float*)d_in[23];
    const float* mpW  = (const float*)d_in[24];
    const float* mpb  = (const float*)d_in[25];
    const float* pmW  = (const float*)d_in[26];
    const float* pmb  = (const float*)d_in[27];
    const float* fc1W = (const float*)d_in[28];
    const float* fc1b = (const float*)d_in[29];
    const float* fc2W = (const float*)d_in[30];
    const float* fc2b = (const float*)d_in[31];

    float* ws   = (float*)d_ws;
    float* xm   = ws;                 // 2048*64
    float* xp   = xm + 131072;        // 4096*64
    float* aggm = xp + 262144;        // 2048*64  (aggm+aggp contiguous for one memset)
    float* aggp = aggm + 131072;      // 4096*64
    float* Qm   = aggp + 262144;
    float* Kp   = Qm + 131072;
    float* Vp   = Kp + 262144;
    float* Qp   = Vp + 262144;
    float* Km   = Qp + 262144;
    float* Vm   = Km + 131072;
    float* Hm   = Vm + 131072;
    float* Hp   = Hm + 131072;
    float* pool = Hp + 262144;        // 32*128 (+64 counts, contiguous for one memset)
    float* cnt  = pool + 4096;

    k_node_lin<<<N_MOL + N_PROT, 64, 0, stream>>>(mol_x, prot_x, nlmW, nlmb, nlpW, nlpb, xm, xp);

    for (int l = 0; l < 3; ++l) {
        hipMemsetAsync(aggm, 0, (size_t)(131072 + 262144) * sizeof(float), stream);
        k_scatter<<<(E_MOL + E_PROT) / 4, 256, 0, stream>>>(
            xm, xp, mol_ea, prot_ea, mol_ei, prot_ei, elmW, elmb, elpW, elpb, aggm, aggp);
        k_update<<<N_MOL + N_PROT, 64, 0, stream>>>(
            xm, xp, aggm, aggp,
            mcW1 + l * 4096, mcb1 + l * 64, mcW2 + l * 4096, mcb2 + l * 64,
            pcW1 + l * 4096, pcb1 + l * 64, pcW2 + l * 4096, pcb2 + l * 64);
    }

    k_qkv<<<18432, 64, 0, stream>>>(xm, xp, mpW, mpb, pmW, pmb, Qm, Kp, Vp, Qp, Km, Vm);
    k_attn<<<N_MOL / TQ + N_PROT / TQ, 256, 0, stream>>>(Qm, Kp, Vp, Qp, Km, Vm, xm, xp, Hm, Hp);

    hipMemsetAsync(pool, 0, (size_t)(4096 + 64) * sizeof(float), stream);
    k_pool<<<N_MOL + N_PROT, 64, 0, stream>>>(Hm, Hp, mol_b, prot_b, pool, cnt);
    k_final<<<BATCH, 64, 0, stream>>>(pool, cnt, fc1W, fc1b, fc2W, fc2b, (float*)d_out);
}

// Round 3
// 471.127 us; speedup vs baseline: 3.8579x; 1.2400x over previous
//
#include <hip/hip_runtime.h>
#include <math.h>

#define HID 64
#define HEADS 4
#define HDIM 16
#define N_MOL 2048
#define N_PROT 4096
#define E_MOL 32768
#define E_PROT 131072
#define BATCH 32

// attention tiling
#define TQA 8          // queries per block
#define TKA 32         // keys per LDS tile
#define KSTA 68        // LDS row stride (words): 272B, 16B-aligned, banks balanced
#define SCHUNK 2       // key-dimension split

#define DOT4(a, b) ((a).x*(b).x + (a).y*(b).y + (a).z*(b).z + (a).w*(b).w)

// ---------------------------------------------------------------------------
// Node input linear: 4 nodes per 256-thread block, one wave per node.
__global__ void k_node_lin(const float* __restrict__ mol_x, const float* __restrict__ prot_x,
                           const float* __restrict__ Wm, const float* __restrict__ bm,
                           const float* __restrict__ Wp, const float* __restrict__ bp,
                           float* __restrict__ xm, float* __restrict__ xp) {
    int w = threadIdx.x >> 6, t = threadIdx.x & 63;
    int n = blockIdx.x * 4 + w;
    if (n < N_MOL) {
        const float* xr = mol_x + n * 11;
        float acc = bm[t];
#pragma unroll
        for (int i = 0; i < 11; ++i) acc += xr[i] * Wm[i * HID + t];
        xm[n * HID + t] = acc;
    } else {
        int p = n - N_MOL;
        const float* xr = prot_x + p * 15;
        float acc = bp[t];
#pragma unroll
        for (int i = 0; i < 15; ++i) acc += xr[i] * Wp[i * HID + t];
        xp[p * HID + t] = acc;
    }
}

// ---------------------------------------------------------------------------
// Fused edge-linear + message + scatter-add. 4 edges per 256-thread block.
__global__ void k_scatter(const float* __restrict__ xm, const float* __restrict__ xp,
                          const float* __restrict__ mol_ea, const float* __restrict__ prot_ea,
                          const int* __restrict__ mol_ei, const int* __restrict__ prot_ei,
                          const float* __restrict__ Wem, const float* __restrict__ bem,
                          const float* __restrict__ Wep, const float* __restrict__ bep,
                          float* __restrict__ aggm, float* __restrict__ aggp) {
    int t = threadIdx.x & 63;
    int sub = threadIdx.x >> 6;
    int blk = blockIdx.x;
    if (blk < E_MOL / 4) {
        int e = blk * 4 + sub;
        int src = mol_ei[e], dst = mol_ei[E_MOL + e];
        const float* ea = mol_ea + e * 10;
        float acc = bem[t];
#pragma unroll
        for (int i = 0; i < 10; ++i) acc += ea[i] * Wem[i * HID + t];
        float v = fmaxf(acc + xm[src * HID + t], 0.f);
        unsafeAtomicAdd(&aggm[dst * HID + t], v);
    } else {
        int e = (blk - E_MOL / 4) * 4 + sub;
        int src = prot_ei[e], dst = prot_ei[E_PROT + e];
        const float* ea = prot_ea + e * 10;
        float acc = bep[t];
#pragma unroll
        for (int i = 0; i < 10; ++i) acc += ea[i] * Wep[i * HID + t];
        float v = fmaxf(acc + xp[src * HID + t], 0.f);
        unsafeAtomicAdd(&aggp[dst * HID + t], v);
    }
}

// ---------------------------------------------------------------------------
// GINE node update: h=x+agg; x_new=relu(relu(h@W1+b1)@W2+b2). 4 nodes/block.
__global__ void k_update(float* __restrict__ xm, float* __restrict__ xp,
                         const float* __restrict__ aggm, const float* __restrict__ aggp,
                         const float* __restrict__ W1m, const float* __restrict__ b1m,
                         const float* __restrict__ W2m, const float* __restrict__ b2m,
                         const float* __restrict__ W1p, const float* __restrict__ b1p,
                         const float* __restrict__ W2p, const float* __restrict__ b2p) {
    __shared__ float h0[4][HID];
    __shared__ float h1[4][HID];
    int w = threadIdx.x >> 6, t = threadIdx.x & 63;
    int nb = blockIdx.x * 4 + w;
    float* x;
    const float *agg, *W1, *b1, *W2, *b2;
    int n;
    if (nb < N_MOL) {
        n = nb; x = xm; agg = aggm; W1 = W1m; b1 = b1m; W2 = W2m; b2 = b2m;
    } else {
        n = nb - N_MOL; x = xp; agg = aggp; W1 = W1p; b1 = b1p; W2 = W2p; b2 = b2p;
    }
    h0[w][t] = x[n * HID + t] + agg[n * HID + t];
    __syncthreads();
    float acc = b1[t];
#pragma unroll 8
    for (int k = 0; k < HID; ++k) acc += h0[w][k] * W1[k * HID + t];
    h1[w][t] = fmaxf(acc, 0.f);
    __syncthreads();
    float acc2 = b2[t];
#pragma unroll 8
    for (int k = 0; k < HID; ++k) acc2 += h1[w][k] * W2[k * HID + t];
    x[n * HID + t] = fmaxf(acc2, 0.f);
}

// ---------------------------------------------------------------------------
// QKV projections: 4 rows per 256-thread block, one wave per row.
__global__ void k_qkv(const float* __restrict__ xm, const float* __restrict__ xp,
                      const float* __restrict__ mpW, const float* __restrict__ mpb,
                      const float* __restrict__ pmW, const float* __restrict__ pmb,
                      float* __restrict__ Qm, float* __restrict__ Kp, float* __restrict__ Vp,
                      float* __restrict__ Qp, float* __restrict__ Km, float* __restrict__ Vm) {
    __shared__ float row[4][HID];
    int w = threadIdx.x >> 6, t = threadIdx.x & 63;
    int b = blockIdx.x * 4 + w;
    const float *src, *W, *bias;
    float* dst;
    int n;
    if (b < 2048)       { n = b;         src = xm; W = mpW;        bias = mpb;       dst = Qm; }
    else if (b < 6144)  { n = b - 2048;  src = xp; W = mpW + 4096; bias = mpb + 64;  dst = Kp; }
    else if (b < 10240) { n = b - 6144;  src = xp; W = mpW + 8192; bias = mpb + 128; dst = Vp; }
    else if (b < 14336) { n = b - 10240; src = xp; W = pmW;        bias = pmb;       dst = Qp; }
    else if (b < 16384) { n = b - 14336; src = xm; W = pmW + 4096; bias = pmb + 64;  dst = Km; }
    else                { n = b - 16384; src = xm; W = pmW + 8192; bias = pmb + 128; dst = Vm; }
    row[w][t] = src[n * HID + t];
    __syncthreads();
    float acc = bias[t];
#pragma unroll 8
    for (int k = 0; k < HID; ++k) acc += row[w][k] * W[k * HID + t];
    dst[n * HID + t] = acc;
}

// ---------------------------------------------------------------------------
// online-softmax partial state helpers
__device__ inline void upd4(float4& A, const float4 v0, const float4 v1,
                            float p0, float p1, float al) {
    A.x = fmaf(p1, v1.x, fmaf(p0, v0.x, A.x * al));
    A.y = fmaf(p1, v1.y, fmaf(p0, v0.y, A.y * al));
    A.z = fmaf(p1, v1.z, fmaf(p0, v0.z, A.z * al));
    A.w = fmaf(p1, v1.w, fmaf(p0, v0.w, A.w * al));
}

__device__ inline void merge4(float4& A, const float4 B, float c1, float c2) {
    A.x = A.x * c1 + B.x * c2;
    A.y = A.y * c1 + B.y * c2;
    A.z = A.z * c1 + B.z * c2;
    A.w = A.w * c1 + B.w * c2;
}

__device__ inline float4 shfl4(const float4 a, int off) {
    float4 r;
    r.x = __shfl_xor(a.x, off, 64); r.y = __shfl_xor(a.y, off, 64);
    r.z = __shfl_xor(a.z, off, 64); r.w = __shfl_xor(a.w, off, 64);
    return r;
}

// ---------------------------------------------------------------------------
// Tiled cross attention with key-split. Block = 8 queries x 4 heads x half the
// keys; 256 threads. Lane map (per wave): sub=t&15 (key subset), h=(t>>4)&3.
// 64 unique float4 LDS reads per instr spread evenly over all 32 banks.
// Each thread: 2 queries, 2 keys/tile, one rescale per 2 keys.
// Writes partial (m,l,acc[16]) per (q,h,chunk); k_attn_merge combines.
__global__ __launch_bounds__(256) void k_attn(
    const float* __restrict__ Qm, const float* __restrict__ Kp, const float* __restrict__ Vp,
    const float* __restrict__ Qp, const float* __restrict__ Km, const float* __restrict__ Vm,
    float* __restrict__ part_m, float* __restrict__ part_p) {
    __shared__ float Kl[TKA * KSTA];
    __shared__ float Vl[TKA * KSTA];

    int t = threadIdx.x;
    const float *Q, *K, *V;
    float* part;
    int q0, Nk, chunk;
    {
        int b = blockIdx.x;
        const int MOLB = (N_MOL / TQA) * SCHUNK;   // 512
        if (b < MOLB) {
            chunk = b & 1; q0 = (b >> 1) * TQA;
            Q = Qm; K = Kp; V = Vp; part = part_m; Nk = N_PROT;
        } else {
            b -= MOLB;
            chunk = b & 1; q0 = (b >> 1) * TQA;
            Q = Qp; K = Km; V = Vm; part = part_p; Nk = N_MOL;
        }
    }
    int kbeg = chunk * (Nk / 2), kend = kbeg + Nk / 2;

    int sub = t & 15, h = (t >> 4) & 3, qg = t >> 6;
    int qia = q0 + qg * 2, qib = qia + 1;

    const float4* Qa = (const float4*)(Q + qia * HID + h * HDIM);
    const float4* Qb = (const float4*)(Q + qib * HID + h * HDIM);
    float4 qa0 = Qa[0], qa1 = Qa[1], qa2 = Qa[2], qa3 = Qa[3];
    float4 qb0 = Qb[0], qb1 = Qb[1], qb2 = Qb[2], qb3 = Qb[3];
    const float sc = 0.25f;   // 1/sqrt(HDIM)
    qa0.x*=sc; qa0.y*=sc; qa0.z*=sc; qa0.w*=sc; qa1.x*=sc; qa1.y*=sc; qa1.z*=sc; qa1.w*=sc;
    qa2.x*=sc; qa2.y*=sc; qa2.z*=sc; qa2.w*=sc; qa3.x*=sc; qa3.y*=sc; qa3.z*=sc; qa3.w*=sc;
    qb0.x*=sc; qb0.y*=sc; qb0.z*=sc; qb0.w*=sc; qb1.x*=sc; qb1.y*=sc; qb1.z*=sc; qb1.w*=sc;
    qb2.x*=sc; qb2.y*=sc; qb2.z*=sc; qb2.w*=sc; qb3.x*=sc; qb3.y*=sc; qb3.z*=sc; qb3.w*=sc;

    float ma = -INFINITY, la = 0.f, mb = -INFINITY, lb = 0.f;
    float4 Aa0 = {0,0,0,0}, Aa1 = {0,0,0,0}, Aa2 = {0,0,0,0}, Aa3 = {0,0,0,0};
    float4 Ab0 = {0,0,0,0}, Ab1 = {0,0,0,0}, Ab2 = {0,0,0,0}, Ab3 = {0,0,0,0};

    for (int kt = kbeg; kt < kend; kt += TKA) {
        __syncthreads();
        const float4* Kg = (const float4*)(K + kt * HID);
        const float4* Vg = (const float4*)(V + kt * HID);
#pragma unroll
        for (int j = 0; j < 2; ++j) {
            int idx = t + j * 256;                 // 0..511 float4s (32 rows x 16)
            int r = idx >> 4, c = (idx & 15) << 2;
            *(float4*)&Kl[r * KSTA + c] = Kg[idx];
            *(float4*)&Vl[r * KSTA + c] = Vg[idx];
        }
        __syncthreads();

        int k0 = sub, k1 = sub + 16;
        const float4* Kr0 = (const float4*)&Kl[k0 * KSTA + h * HDIM];
        const float4* Kr1 = (const float4*)&Kl[k1 * KSTA + h * HDIM];
        float4 x0 = Kr0[0], x1 = Kr0[1], x2 = Kr0[2], x3 = Kr0[3];
        float4 y0 = Kr1[0], y1 = Kr1[1], y2 = Kr1[2], y3 = Kr1[3];

        float s0a = DOT4(x0,qa0) + DOT4(x1,qa1) + DOT4(x2,qa2) + DOT4(x3,qa3);
        float s0b = DOT4(x0,qb0) + DOT4(x1,qb1) + DOT4(x2,qb2) + DOT4(x3,qb3);
        float s1a = DOT4(y0,qa0) + DOT4(y1,qa1) + DOT4(y2,qa2) + DOT4(y3,qa3);
        float s1b = DOT4(y0,qb0) + DOT4(y1,qb1) + DOT4(y2,qb2) + DOT4(y3,qb3);

        float mna = fmaxf(ma, fmaxf(s0a, s1a));
        float ala = __expf(ma - mna), p0a = __expf(s0a - mna), p1a = __expf(s1a - mna);
        la = la * ala + p0a + p1a;
        float mnb = fmaxf(mb, fmaxf(s0b, s1b));
        float alb = __expf(mb - mnb), p0b = __expf(s0b - mnb), p1b = __expf(s1b - mnb);
        lb = lb * alb + p0b + p1b;

        const float4* Vr0 = (const float4*)&Vl[k0 * KSTA + h * HDIM];
        const float4* Vr1 = (const float4*)&Vl[k1 * KSTA + h * HDIM];
        float4 v00 = Vr0[0], v01 = Vr0[1], v02 = Vr0[2], v03 = Vr0[3];
        float4 v10 = Vr1[0], v11 = Vr1[1], v12 = Vr1[2], v13 = Vr1[3];

        upd4(Aa0, v00, v10, p0a, p1a, ala);
        upd4(Aa1, v01, v11, p0a, p1a, ala);
        upd4(Aa2, v02, v12, p0a, p1a, ala);
        upd4(Aa3, v03, v13, p0a, p1a, ala);
        upd4(Ab0, v00, v10, p0b, p1b, alb);
        upd4(Ab1, v01, v11, p0b, p1b, alb);
        upd4(Ab2, v02, v12, p0b, p1b, alb);
        upd4(Ab3, v03, v13, p0b, p1b, alb);
        ma = mna; mb = mnb;
    }

    // merge 16 partial states across sub lanes (lane bits 0..3)
#pragma unroll
    for (int off = 1; off < 16; off <<= 1) {
        {
            float m2 = __shfl_xor(ma, off, 64);
            float l2 = __shfl_xor(la, off, 64);
            float4 B0 = shfl4(Aa0, off), B1 = shfl4(Aa1, off), B2 = shfl4(Aa2, off), B3 = shfl4(Aa3, off);
            float mn = fmaxf(ma, m2);
            float c1 = __expf(ma - mn), c2 = __expf(m2 - mn);
            la = la * c1 + l2 * c2;
            merge4(Aa0, B0, c1, c2); merge4(Aa1, B1, c1, c2);
            merge4(Aa2, B2, c1, c2); merge4(Aa3, B3, c1, c2);
            ma = mn;
        }
        {
            float m2 = __shfl_xor(mb, off, 64);
            float l2 = __shfl_xor(lb, off, 64);
            float4 B0 = shfl4(Ab0, off), B1 = shfl4(Ab1, off), B2 = shfl4(Ab2, off), B3 = shfl4(Ab3, off);
            float mn = fmaxf(mb, m2);
            float c1 = __expf(mb - mn), c2 = __expf(m2 - mn);
            lb = lb * c1 + l2 * c2;
            merge4(Ab0, B0, c1, c2); merge4(Ab1, B1, c1, c2);
            merge4(Ab2, B2, c1, c2); merge4(Ab3, B3, c1, c2);
            mb = mn;
        }
    }

    if (sub == 0) {
        float* pa = part + (size_t)((qia * HEADS + h) * SCHUNK + chunk) * 20;
        pa[0] = ma; pa[1] = la;
        *(float4*)&pa[4] = Aa0; *(float4*)&pa[8] = Aa1;
        *(float4*)&pa[12] = Aa2; *(float4*)&pa[16] = Aa3;
        float* pb = part + (size_t)((qib * HEADS + h) * SCHUNK + chunk) * 20;
        pb[0] = mb; pb[1] = lb;
        *(float4*)&pb[4] = Ab0; *(float4*)&pb[8] = Ab1;
        *(float4*)&pb[12] = Ab2; *(float4*)&pb[16] = Ab3;
    }
}

// ---------------------------------------------------------------------------
// Merge the SCHUNK partial states per (q,h), normalize, add residual, write H.
// Thread <-> (q,h); consecutive threads write consecutive 64B segments.
__global__ void k_attn_merge(const float* __restrict__ part_m, const float* __restrict__ part_p,
                             const float* __restrict__ xm, const float* __restrict__ xp,
                             float* __restrict__ Hm, float* __restrict__ Hp) {
    int gi = blockIdx.x * 256 + threadIdx.x;
    const float *part, *X;
    float* H;
    if (gi < N_MOL * HEADS) { part = part_m; X = xm; H = Hm; }
    else { gi -= N_MOL * HEADS; part = part_p; X = xp; H = Hp; }
    int q = gi >> 2, h = gi & 3;
    const float* p0 = part + (size_t)gi * SCHUNK * 20;
    const float* p1 = p0 + 20;
    float m0 = p0[0], l0 = p0[1], m1 = p1[0], l1 = p1[1];
    float mn = fmaxf(m0, m1);
    float a0 = __expf(m0 - mn), a1 = __expf(m1 - mn);
    float inv = 1.f / (l0 * a0 + l1 * a1);
    a0 *= inv; a1 *= inv;
    const float4* A0 = (const float4*)(p0 + 4);
    const float4* A1 = (const float4*)(p1 + 4);
    const float4* Xr = (const float4*)(X + q * HID + h * HDIM);
    float4* Hr = (float4*)(H + q * HID + h * HDIM);
#pragma unroll
    for (int j = 0; j < 4; ++j) {
        float4 o;
        o.x = A0[j].x * a0 + A1[j].x * a1 + Xr[j].x;
        o.y = A0[j].y * a0 + A1[j].y * a1 + Xr[j].y;
        o.z = A0[j].z * a0 + A1[j].z * a1 + Xr[j].z;
        o.w = A0[j].w * a0 + A1[j].w * a1 + Xr[j].w;
        Hr[j] = o;
    }
}

// ---------------------------------------------------------------------------
// Per-batch mean-pool (sums + counts via atomics). 4 nodes per block.
__global__ void k_pool(const float* __restrict__ Hm, const float* __restrict__ Hp,
                       const int* __restrict__ mb, const int* __restrict__ pb,
                       float* __restrict__ pool, float* __restrict__ cnt) {
    int w = threadIdx.x >> 6, t = threadIdx.x & 63;
    int n = blockIdx.x * 4 + w;
    if (n < N_MOL) {
        int b = mb[n];
        unsafeAtomicAdd(&pool[b * 128 + t], Hm[n * HID + t]);
        if (t == 0) unsafeAtomicAdd(&cnt[b * 2 + 0], 1.f);
    } else {
        int p = n - N_MOL;
        int b = pb[p];
        unsafeAtomicAdd(&pool[b * 128 + 64 + t], Hp[p * HID + t]);
        if (t == 0) unsafeAtomicAdd(&cnt[b * 2 + 1], 1.f);
    }
}

// ---------------------------------------------------------------------------
// Head: z = [mean_mol | mean_prot]; relu(z@fc1+b1)@fc2+b2 -> sigmoid.
__global__ void k_final(const float* __restrict__ pool, const float* __restrict__ cnt,
                        const float* __restrict__ fc1W, const float* __restrict__ fc1b,
                        const float* __restrict__ fc2W, const float* __restrict__ fc2b,
                        float* __restrict__ out) {
    __shared__ float z[128];
    int b = blockIdx.x, t = threadIdx.x;
    float cm = fmaxf(cnt[b * 2 + 0], 1.f), cp = fmaxf(cnt[b * 2 + 1], 1.f);
    z[t] = pool[b * 128 + t] / cm;
    z[64 + t] = pool[b * 128 + 64 + t] / cp;
    __syncthreads();
    float acc = fc1b[t];
#pragma unroll 8
    for (int k = 0; k < 128; ++k) acc += z[k] * fc1W[k * 64 + t];
    float hv = fmaxf(acc, 0.f);
    float prod = hv * fc2W[t];
#pragma unroll
    for (int off = 32; off > 0; off >>= 1) prod += __shfl_xor(prod, off, 64);
    if (t == 0) out[b] = 1.f / (1.f + __expf(-(prod + fc2b[0])));
}

// ---------------------------------------------------------------------------
extern "C" void kernel_launch(void* const* d_in, const int* in_sizes, int n_in,
                              void* d_out, int out_size, void* d_ws, size_t ws_size,
                              hipStream_t stream) {
    const float* mol_x   = (const float*)d_in[0];
    const float* prot_x  = (const float*)d_in[1];
    const float* mol_ea  = (const float*)d_in[2];
    const float* prot_ea = (const float*)d_in[3];
    const int*   mol_ei  = (const int*)d_in[4];
    const int*   prot_ei = (const int*)d_in[5];
    const int*   mol_b   = (const int*)d_in[6];
    const int*   prot_b  = (const int*)d_in[7];
    const float* nlmW = (const float*)d_in[8];
    const float* nlmb = (const float*)d_in[9];
    const float* nlpW = (const float*)d_in[10];
    const float* nlpb = (const float*)d_in[11];
    const float* elmW = (const float*)d_in[12];
    const float* elmb = (const float*)d_in[13];
    const float* elpW = (const float*)d_in[14];
    const float* elpb = (const float*)d_in[15];
    const float* mcW1 = (const float*)d_in[16];
    const float* mcb1 = (const float*)d_in[17];
    const float* mcW2 = (const float*)d_in[18];
    const float* mcb2 = (const float*)d_in[19];
    const float* pcW1 = (const float*)d_in[20];
    const float* pcb1 = (const float*)d_in[21];
    const float* pcW2 = (const float*)d_in[22];
    const float* pcb2 = (const float*)d_in[23];
    const float* mpW  = (const float*)d_in[24];
    const float* mpb  = (const float*)d_in[25];
    const float* pmW  = (const float*)d_in[26];
    const float* pmb  = (const float*)d_in[27];
    const float* fc1W = (const float*)d_in[28];
    const float* fc1b = (const float*)d_in[29];
    const float* fc2W = (const float*)d_in[30];
    const float* fc2b = (const float*)d_in[31];

    float* ws    = (float*)d_ws;
    float* xm    = ws;                  // 2048*64
    float* xp    = xm + 131072;         // 4096*64
    float* aggm  = xp + 262144;         // contiguous with aggp for one memset
    float* aggp  = aggm + 131072;
    float* Qm    = aggp + 262144;
    float* Kp    = Qm + 131072;
    float* Vp    = Kp + 262144;
    float* Qp    = Vp + 262144;
    float* Km    = Qp + 262144;
    float* Vm    = Km + 131072;
    float* Hm    = Vm + 131072;
    float* Hp    = Hm + 131072;
    float* pool  = Hp + 262144;         // 32*128 (+64 counts)
    float* cnt   = pool + 4096;
    float* partm = cnt + 64;            // 2048*4*2*20 = 327680
    float* partp = partm + 327680;      // 4096*4*2*20 = 655360

    k_node_lin<<<(N_MOL + N_PROT) / 4, 256, 0, stream>>>(mol_x, prot_x, nlmW, nlmb, nlpW, nlpb, xm, xp);

    for (int l = 0; l < 3; ++l) {
        hipMemsetAsync(aggm, 0, (size_t)(131072 + 262144) * sizeof(float), stream);
        k_scatter<<<(E_MOL + E_PROT) / 4, 256, 0, stream>>>(
            xm, xp, mol_ea, prot_ea, mol_ei, prot_ei, elmW, elmb, elpW, elpb, aggm, aggp);
        k_update<<<(N_MOL + N_PROT) / 4, 256, 0, stream>>>(
            xm, xp, aggm, aggp,
            mcW1 + l * 4096, mcb1 + l * 64, mcW2 + l * 4096, mcb2 + l * 64,
            pcW1 + l * 4096, pcb1 + l * 64, pcW2 + l * 4096, pcb2 + l * 64);
    }

    k_qkv<<<18432 / 4, 256, 0, stream>>>(xm, xp, mpW, mpb, pmW, pmb, Qm, Kp, Vp, Qp, Km, Vm);
    k_attn<<<(N_MOL / TQA + N_PROT / TQA) * SCHUNK, 256, 0, stream>>>(
        Qm, Kp, Vp, Qp, Km, Vm, partm, partp);
    k_attn_merge<<<(N_MOL + N_PROT) * HEADS / 256, 256, 0, stream>>>(
        partm, partp, xm, xp, Hm, Hp);

    hipMemsetAsync(pool, 0, (size_t)(4096 + 64) * sizeof(float), stream);
    k_pool<<<(N_MOL + N_PROT) / 4, 256, 0, stream>>>(Hm, Hp, mol_b, prot_b, pool, cnt);
    k_final<<<BATCH, 64, 0, stream>>>(pool, cnt, fc1W, fc1b, fc2W, fc2b, (float*)d_out);
}

// Round 4
// 450.410 us; speedup vs baseline: 4.0353x; 1.0460x over previous
//
#include <hip/hip_runtime.h>
#include <math.h>

#define HID 64
#define HEADS 4
#define HDIM 16
#define N_MOL 2048
#define N_PROT 4096
#define E_MOL 32768
#define E_PROT 131072
#define BATCH 32
#define N_TOT (N_MOL + N_PROT)
#define E_TOT (E_MOL + E_PROT)

// attention tiling
#define TQA 16         // queries per block
#define TKA 32         // keys per LDS tile
#define KSTA 68        // LDS row stride (words)
#define CH_MOL 4       // key chunks for mol queries (4096 keys / 1024)
#define CH_PROT 2      // key chunks for prot queries (2048 keys / 1024)
#define KCHUNK 1024    // keys per block (uniform work)

#define DOT4(a, b) ((a).x*(b).x + (a).y*(b).y + (a).z*(b).z + (a).w*(b).w)

// ---------------------------------------------------------------------------
// Node input linear: 4 nodes per 256-thread block, one wave per node.
__global__ void k_node_lin(const float* __restrict__ mol_x, const float* __restrict__ prot_x,
                           const float* __restrict__ Wm, const float* __restrict__ bm,
                           const float* __restrict__ Wp, const float* __restrict__ bp,
                           float* __restrict__ xm, float* __restrict__ xp) {
    int w = threadIdx.x >> 6, t = threadIdx.x & 63;
    int n = blockIdx.x * 4 + w;
    if (n < N_MOL) {
        const float* xr = mol_x + n * 11;
        float acc = bm[t];
#pragma unroll
        for (int i = 0; i < 11; ++i) acc += xr[i] * Wm[i * HID + t];
        xm[n * HID + t] = acc;
    } else {
        int p = n - N_MOL;
        const float* xr = prot_x + p * 15;
        float acc = bp[t];
#pragma unroll
        for (int i = 0; i < 15; ++i) acc += xr[i] * Wp[i * HID + t];
        xp[p * HID + t] = acc;
    }
}

// ---------------------------------------------------------------------------
// CSR build: degree count, exclusive scan, fill edge lists.
__global__ void k_deg(const int* __restrict__ mol_ei, const int* __restrict__ prot_ei,
                      int* __restrict__ deg) {
    int e = blockIdx.x * 256 + threadIdx.x;
    if (e < E_MOL) atomicAdd(&deg[mol_ei[E_MOL + e]], 1);
    else atomicAdd(&deg[N_MOL + prot_ei[E_PROT + (e - E_MOL)]], 1);
}

__global__ void k_scan(const int* __restrict__ deg, int* __restrict__ rowptr,
                       int* __restrict__ cursor) {
    __shared__ int waveSums[4];
    int t = threadIdx.x;                    // 256 threads, 24 nodes each
    int base = t * 24;
    int local[24];
    int s = 0;
#pragma unroll
    for (int i = 0; i < 24; ++i) { local[i] = s; s += deg[base + i]; }
    int lane = t & 63, w = t >> 6;
    int pref = s;
#pragma unroll
    for (int off = 1; off < 64; off <<= 1) {
        int v = __shfl_up(pref, off, 64);
        if (lane >= off) pref += v;
    }
    if (lane == 63) waveSums[w] = pref;
    __syncthreads();
    int waveOff = 0;
    for (int i = 0; i < w; ++i) waveOff += waveSums[i];
    int excl = pref - s + waveOff;
#pragma unroll
    for (int i = 0; i < 24; ++i) {
        rowptr[base + i] = excl + local[i];
        cursor[base + i] = excl + local[i];
    }
    if (t == 255) rowptr[N_TOT] = excl + s;
}

__global__ void k_fill(const int* __restrict__ mol_ei, const int* __restrict__ prot_ei,
                       int* __restrict__ cursor, int* __restrict__ eidx) {
    int e = blockIdx.x * 256 + threadIdx.x;
    int node;
    if (e < E_MOL) node = mol_ei[E_MOL + e];
    else node = N_MOL + prot_ei[E_PROT + (e - E_MOL)];
    int pos = atomicAdd(&cursor[node], 1);
    eidx[pos] = e;     // global edge id (prot offset by E_MOL)
}

// ---------------------------------------------------------------------------
// Fused GINE layer: CSR gather (edge-lin recomputed, no atomics) + node MLP.
// 4 nodes per 256-thread block, one wave per node. Reads xin, writes xout.
__global__ void k_gine(const float* __restrict__ xin_m, const float* __restrict__ xin_p,
                       float* __restrict__ xout_m, float* __restrict__ xout_p,
                       const float* __restrict__ mol_ea, const float* __restrict__ prot_ea,
                       const int* __restrict__ mol_ei, const int* __restrict__ prot_ei,
                       const float* __restrict__ Wem, const float* __restrict__ bem,
                       const float* __restrict__ Wep, const float* __restrict__ bep,
                       const float* __restrict__ W1m, const float* __restrict__ b1m,
                       const float* __restrict__ W2m, const float* __restrict__ b2m,
                       const float* __restrict__ W1p, const float* __restrict__ b1p,
                       const float* __restrict__ W2p, const float* __restrict__ b2p,
                       const int* __restrict__ rowptr, const int* __restrict__ eidx) {
    __shared__ float h0[4][HID];
    __shared__ float h1[4][HID];
    int w = threadIdx.x >> 6, t = threadIdx.x & 63;
    int nb = blockIdx.x * 4 + w;
    bool isMol = nb < N_MOL;
    const float* x = isMol ? xin_m : xin_p;
    float* xo = isMol ? xout_m : xout_p;
    int n = isMol ? nb : nb - N_MOL;
    const float* We = isMol ? Wem : Wep;
    float bt = isMol ? bem[t] : bep[t];
    const float* ea_base = isMol ? mol_ea : prot_ea;
    const int* srcarr = isMol ? mol_ei : prot_ei;
    int ebias = isMol ? 0 : E_MOL;
    float wcol[10];
#pragma unroll
    for (int i = 0; i < 10; ++i) wcol[i] = We[i * HID + t];
    float agg = 0.f;
    int beg = rowptr[nb], end = rowptr[nb + 1];
    for (int j = beg; j < end; ++j) {
        int e = eidx[j] - ebias;
        int src = srcarr[e];
        const float* ea = ea_base + (size_t)e * 10;
        float m = bt;
#pragma unroll
        for (int i = 0; i < 10; ++i) m = fmaf(ea[i], wcol[i], m);
        m += x[src * HID + t];
        agg += fmaxf(m, 0.f);
    }
    h0[w][t] = x[n * HID + t] + agg;
    __syncthreads();
    const float* W1 = isMol ? W1m : W1p;
    const float* W2 = isMol ? W2m : W2p;
    float acc = isMol ? b1m[t] : b1p[t];
    const float4* h0v = (const float4*)h0[w];
#pragma unroll
    for (int k = 0; k < 16; ++k) {
        float4 hv = h0v[k];
        acc = fmaf(hv.x, W1[(4 * k + 0) * HID + t], acc);
        acc = fmaf(hv.y, W1[(4 * k + 1) * HID + t], acc);
        acc = fmaf(hv.z, W1[(4 * k + 2) * HID + t], acc);
        acc = fmaf(hv.w, W1[(4 * k + 3) * HID + t], acc);
    }
    h1[w][t] = fmaxf(acc, 0.f);
    __syncthreads();
    float acc2 = isMol ? b2m[t] : b2p[t];
    const float4* h1v = (const float4*)h1[w];
#pragma unroll
    for (int k = 0; k < 16; ++k) {
        float4 hv = h1v[k];
        acc2 = fmaf(hv.x, W2[(4 * k + 0) * HID + t], acc2);
        acc2 = fmaf(hv.y, W2[(4 * k + 1) * HID + t], acc2);
        acc2 = fmaf(hv.z, W2[(4 * k + 2) * HID + t], acc2);
        acc2 = fmaf(hv.w, W2[(4 * k + 3) * HID + t], acc2);
    }
    xo[n * HID + t] = fmaxf(acc2, 0.f);
}

// ---------------------------------------------------------------------------
// QKV projections: 4 rows per 256-thread block, one wave per row.
__global__ void k_qkv(const float* __restrict__ xm, const float* __restrict__ xp,
                      const float* __restrict__ mpW, const float* __restrict__ mpb,
                      const float* __restrict__ pmW, const float* __restrict__ pmb,
                      float* __restrict__ Qm, float* __restrict__ Kp, float* __restrict__ Vp,
                      float* __restrict__ Qp, float* __restrict__ Km, float* __restrict__ Vm) {
    __shared__ float row[4][HID];
    int w = threadIdx.x >> 6, t = threadIdx.x & 63;
    int b = blockIdx.x * 4 + w;
    const float *src, *W, *bias;
    float* dst;
    int n;
    if (b < 2048)       { n = b;         src = xm; W = mpW;        bias = mpb;       dst = Qm; }
    else if (b < 6144)  { n = b - 2048;  src = xp; W = mpW + 4096; bias = mpb + 64;  dst = Kp; }
    else if (b < 10240) { n = b - 6144;  src = xp; W = mpW + 8192; bias = mpb + 128; dst = Vp; }
    else if (b < 14336) { n = b - 10240; src = xp; W = pmW;        bias = pmb;       dst = Qp; }
    else if (b < 16384) { n = b - 14336; src = xm; W = pmW + 4096; bias = pmb + 64;  dst = Km; }
    else                { n = b - 16384; src = xm; W = pmW + 8192; bias = pmb + 128; dst = Vm; }
    row[w][t] = src[n * HID + t];
    __syncthreads();
    float acc = bias[t];
    const float4* rv = (const float4*)row[w];
#pragma unroll
    for (int k = 0; k < 16; ++k) {
        float4 hv = rv[k];
        acc = fmaf(hv.x, W[(4 * k + 0) * HID + t], acc);
        acc = fmaf(hv.y, W[(4 * k + 1) * HID + t], acc);
        acc = fmaf(hv.z, W[(4 * k + 2) * HID + t], acc);
        acc = fmaf(hv.w, W[(4 * k + 3) * HID + t], acc);
    }
    dst[n * HID + t] = acc;
}

// ---------------------------------------------------------------------------
__device__ inline void upd4(float4& A, const float4 v0, const float4 v1,
                            float p0, float p1, float al) {
    A.x = fmaf(p1, v1.x, fmaf(p0, v0.x, A.x * al));
    A.y = fmaf(p1, v1.y, fmaf(p0, v0.y, A.y * al));
    A.z = fmaf(p1, v1.z, fmaf(p0, v0.z, A.z * al));
    A.w = fmaf(p1, v1.w, fmaf(p0, v0.w, A.w * al));
}

__device__ inline void merge4(float4& A, const float4 B, float c1, float c2) {
    A.x = A.x * c1 + B.x * c2;
    A.y = A.y * c1 + B.y * c2;
    A.z = A.z * c1 + B.z * c2;
    A.w = A.w * c1 + B.w * c2;
}

__device__ inline float4 shfl4(const float4 a, int off) {
    float4 r;
    r.x = __shfl_xor(a.x, off, 64); r.y = __shfl_xor(a.y, off, 64);
    r.z = __shfl_xor(a.z, off, 64); r.w = __shfl_xor(a.w, off, 64);
    return r;
}

// ---------------------------------------------------------------------------
// Tiled cross attention, Q_LOCAL=4. Block = 16 queries x 4 heads x 1024 keys.
// Lane map: sub=t&15 (key subset, 2 keys), h=(t>>4)&3, wave=query group of 4.
// One K/V LDS read serves 4 queries. Writes partial (m,l,acc) per (q,h,chunk).
__global__ __launch_bounds__(256) void k_attn(
    const float* __restrict__ Qm, const float* __restrict__ Kp, const float* __restrict__ Vp,
    const float* __restrict__ Qp, const float* __restrict__ Km, const float* __restrict__ Vm,
    float* __restrict__ part_m, float* __restrict__ part_p) {
    __shared__ float Kl[TKA * KSTA];
    __shared__ float Vl[TKA * KSTA];

    int t = threadIdx.x;
    const float *Q, *K, *V;
    float* part;
    int q0, chunk, CH;
    {
        int b = blockIdx.x;
        const int MOLB = (N_MOL / TQA) * CH_MOL;   // 512
        if (b < MOLB) {
            chunk = b & 3; q0 = (b >> 2) * TQA; CH = CH_MOL;
            Q = Qm; K = Kp; V = Vp; part = part_m;
        } else {
            b -= MOLB;
            chunk = b & 1; q0 = (b >> 1) * TQA; CH = CH_PROT;
            Q = Qp; K = Km; V = Vm; part = part_p;
        }
    }
    int kbeg = chunk * KCHUNK, kend = kbeg + KCHUNK;

    int sub = t & 15, h = (t >> 4) & 3, qg = t >> 6;

    float4 q4[4][4];
#pragma unroll
    for (int qq = 0; qq < 4; ++qq) {
        const float4* Qr = (const float4*)(Q + (q0 + qg * 4 + qq) * HID + h * HDIM);
#pragma unroll
        for (int j = 0; j < 4; ++j) {
            float4 v = Qr[j];
            v.x *= 0.25f; v.y *= 0.25f; v.z *= 0.25f; v.w *= 0.25f;   // 1/sqrt(16)
            q4[qq][j] = v;
        }
    }

    float mreg[4], lreg[4];
    float4 A[4][4];
#pragma unroll
    for (int qq = 0; qq < 4; ++qq) {
        mreg[qq] = -INFINITY; lreg[qq] = 0.f;
#pragma unroll
        for (int j = 0; j < 4; ++j) A[qq][j] = (float4){0.f, 0.f, 0.f, 0.f};
    }

    for (int kt = kbeg; kt < kend; kt += TKA) {
        __syncthreads();
        const float4* Kg = (const float4*)(K + kt * HID);
        const float4* Vg = (const float4*)(V + kt * HID);
#pragma unroll
        for (int j = 0; j < 2; ++j) {
            int idx = t + j * 256;                 // 0..511 float4 (32 rows x 16)
            int r = idx >> 4, c = (idx & 15) << 2;
            *(float4*)&Kl[r * KSTA + c] = Kg[idx];
            *(float4*)&Vl[r * KSTA + c] = Vg[idx];
        }
        __syncthreads();

        const float4* Kr0 = (const float4*)&Kl[sub * KSTA + h * HDIM];
        const float4* Kr1 = (const float4*)&Kl[(sub + 16) * KSTA + h * HDIM];
        float4 x0 = Kr0[0], x1 = Kr0[1], x2 = Kr0[2], x3 = Kr0[3];
        float4 y0 = Kr1[0], y1 = Kr1[1], y2 = Kr1[2], y3 = Kr1[3];

        float s0[4], s1[4];
#pragma unroll
        for (int qq = 0; qq < 4; ++qq) {
            s0[qq] = DOT4(x0, q4[qq][0]) + DOT4(x1, q4[qq][1]) + DOT4(x2, q4[qq][2]) + DOT4(x3, q4[qq][3]);
            s1[qq] = DOT4(y0, q4[qq][0]) + DOT4(y1, q4[qq][1]) + DOT4(y2, q4[qq][2]) + DOT4(y3, q4[qq][3]);
        }

        const float4* Vr0 = (const float4*)&Vl[sub * KSTA + h * HDIM];
        const float4* Vr1 = (const float4*)&Vl[(sub + 16) * KSTA + h * HDIM];
        float4 v00 = Vr0[0], v01 = Vr0[1], v02 = Vr0[2], v03 = Vr0[3];
        float4 v10 = Vr1[0], v11 = Vr1[1], v12 = Vr1[2], v13 = Vr1[3];

#pragma unroll
        for (int qq = 0; qq < 4; ++qq) {
            float mn = fmaxf(mreg[qq], fmaxf(s0[qq], s1[qq]));
            float al = __expf(mreg[qq] - mn);
            float p0 = __expf(s0[qq] - mn);
            float p1 = __expf(s1[qq] - mn);
            lreg[qq] = lreg[qq] * al + p0 + p1;
            upd4(A[qq][0], v00, v10, p0, p1, al);
            upd4(A[qq][1], v01, v11, p0, p1, al);
            upd4(A[qq][2], v02, v12, p0, p1, al);
            upd4(A[qq][3], v03, v13, p0, p1, al);
            mreg[qq] = mn;
        }
    }

    // merge 16 partial states across sub lanes (lane bits 0..3)
#pragma unroll
    for (int off = 1; off < 16; off <<= 1) {
#pragma unroll
        for (int qq = 0; qq < 4; ++qq) {
            float m2 = __shfl_xor(mreg[qq], off, 64);
            float l2 = __shfl_xor(lreg[qq], off, 64);
            float4 B0 = shfl4(A[qq][0], off), B1 = shfl4(A[qq][1], off);
            float4 B2 = shfl4(A[qq][2], off), B3 = shfl4(A[qq][3], off);
            float mn = fmaxf(mreg[qq], m2);
            float c1 = __expf(mreg[qq] - mn), c2 = __expf(m2 - mn);
            lreg[qq] = lreg[qq] * c1 + l2 * c2;
            merge4(A[qq][0], B0, c1, c2); merge4(A[qq][1], B1, c1, c2);
            merge4(A[qq][2], B2, c1, c2); merge4(A[qq][3], B3, c1, c2);
            mreg[qq] = mn;
        }
    }

    if (sub == 0) {
#pragma unroll
        for (int qq = 0; qq < 4; ++qq) {
            int qi = q0 + qg * 4 + qq;
            float* pp = part + (size_t)((qi * HEADS + h) * CH + chunk) * 20;
            pp[0] = mreg[qq]; pp[1] = lreg[qq];
            *(float4*)&pp[4] = A[qq][0]; *(float4*)&pp[8] = A[qq][1];
            *(float4*)&pp[12] = A[qq][2]; *(float4*)&pp[16] = A[qq][3];
        }
    }
}

// ---------------------------------------------------------------------------
// Merge chunk partials per (q,h), normalize, add residual, write H.
__global__ void k_attn_merge(const float* __restrict__ part_m, const float* __restrict__ part_p,
                             const float* __restrict__ xm, const float* __restrict__ xp,
                             float* __restrict__ Hm, float* __restrict__ Hp) {
    int gi = blockIdx.x * 256 + threadIdx.x;
    const float *part, *X;
    float* H;
    int CH;
    if (gi < N_MOL * HEADS) { part = part_m; X = xm; H = Hm; CH = CH_MOL; }
    else { gi -= N_MOL * HEADS; part = part_p; X = xp; H = Hp; CH = CH_PROT; }
    int q = gi >> 2, h = gi & 3;
    const float* p0 = part + (size_t)gi * CH * 20;
    float mmax = -INFINITY;
    for (int c = 0; c < CH; ++c) mmax = fmaxf(mmax, p0[c * 20]);
    float lsum = 0.f, wgt[4];
    for (int c = 0; c < CH; ++c) {
        wgt[c] = __expf(p0[c * 20] - mmax);
        lsum += p0[c * 20 + 1] * wgt[c];
    }
    float inv = 1.f / lsum;
    const float4* Xr = (const float4*)(X + q * HID + h * HDIM);
    float4* Hr = (float4*)(H + q * HID + h * HDIM);
#pragma unroll
    for (int j = 0; j < 4; ++j) {
        float4 o = Xr[j];
        for (int c = 0; c < CH; ++c) {
            const float4 Av = *(const float4*)(p0 + c * 20 + 4 + 4 * j);
            float wc = wgt[c] * inv;
            o.x += Av.x * wc; o.y += Av.y * wc; o.z += Av.z * wc; o.w += Av.w * wc;
        }
        Hr[j] = o;
    }
}

// ---------------------------------------------------------------------------
// Per-batch mean-pool (sums + counts via atomics). 4 nodes per block.
__global__ void k_pool(const float* __restrict__ Hm, const float* __restrict__ Hp,
                       const int* __restrict__ mb, const int* __restrict__ pb,
                       float* __restrict__ pool, float* __restrict__ cnt) {
    int w = threadIdx.x >> 6, t = threadIdx.x & 63;
    int n = blockIdx.x * 4 + w;
    if (n < N_MOL) {
        int b = mb[n];
        unsafeAtomicAdd(&pool[b * 128 + t], Hm[n * HID + t]);
        if (t == 0) unsafeAtomicAdd(&cnt[b * 2 + 0], 1.f);
    } else {
        int p = n - N_MOL;
        int b = pb[p];
        unsafeAtomicAdd(&pool[b * 128 + 64 + t], Hp[p * HID + t]);
        if (t == 0) unsafeAtomicAdd(&cnt[b * 2 + 1], 1.f);
    }
}

// ---------------------------------------------------------------------------
// Head: z = [mean_mol | mean_prot]; relu(z@fc1+b1)@fc2+b2 -> sigmoid.
__global__ void k_final(const float* __restrict__ pool, const float* __restrict__ cnt,
                        const float* __restrict__ fc1W, const float* __restrict__ fc1b,
                        const float* __restrict__ fc2W, const float* __restrict__ fc2b,
                        float* __restrict__ out) {
    __shared__ float z[128];
    int b = blockIdx.x, t = threadIdx.x;
    float cm = fmaxf(cnt[b * 2 + 0], 1.f), cp = fmaxf(cnt[b * 2 + 1], 1.f);
    z[t] = pool[b * 128 + t] / cm;
    z[64 + t] = pool[b * 128 + 64 + t] / cp;
    __syncthreads();
    float acc = fc1b[t];
    const float4* zv = (const float4*)z;
#pragma unroll
    for (int k = 0; k < 32; ++k) {
        float4 hv = zv[k];
        acc = fmaf(hv.x, fc1W[(4 * k + 0) * 64 + t], acc);
        acc = fmaf(hv.y, fc1W[(4 * k + 1) * 64 + t], acc);
        acc = fmaf(hv.z, fc1W[(4 * k + 2) * 64 + t], acc);
        acc = fmaf(hv.w, fc1W[(4 * k + 3) * 64 + t], acc);
    }
    float hv = fmaxf(acc, 0.f);
    float prod = hv * fc2W[t];
#pragma unroll
    for (int off = 32; off > 0; off >>= 1) prod += __shfl_xor(prod, off, 64);
    if (t == 0) out[b] = 1.f / (1.f + __expf(-(prod + fc2b[0])));
}

// ---------------------------------------------------------------------------
extern "C" void kernel_launch(void* const* d_in, const int* in_sizes, int n_in,
                              void* d_out, int out_size, void* d_ws, size_t ws_size,
                              hipStream_t stream) {
    const float* mol_x   = (const float*)d_in[0];
    const float* prot_x  = (const float*)d_in[1];
    const float* mol_ea  = (const float*)d_in[2];
    const float* prot_ea = (const float*)d_in[3];
    const int*   mol_ei  = (const int*)d_in[4];
    const int*   prot_ei = (const int*)d_in[5];
    const int*   mol_b   = (const int*)d_in[6];
    const int*   prot_b  = (const int*)d_in[7];
    const float* nlmW = (const float*)d_in[8];
    const float* nlmb = (const float*)d_in[9];
    const float* nlpW = (const float*)d_in[10];
    const float* nlpb = (const float*)d_in[11];
    const float* elmW = (const float*)d_in[12];
    const float* elmb = (const float*)d_in[13];
    const float* elpW = (const float*)d_in[14];
    const float* elpb = (const float*)d_in[15];
    const float* mcW1 = (const float*)d_in[16];
    const float* mcb1 = (const float*)d_in[17];
    const float* mcW2 = (const float*)d_in[18];
    const float* mcb2 = (const float*)d_in[19];
    const float* pcW1 = (const float*)d_in[20];
    const float* pcb1 = (const float*)d_in[21];
    const float* pcW2 = (const float*)d_in[22];
    const float* pcb2 = (const float*)d_in[23];
    const float* mpW  = (const float*)d_in[24];
    const float* mpb  = (const float*)d_in[25];
    const float* pmW  = (const float*)d_in[26];
    const float* pmb  = (const float*)d_in[27];
    const float* fc1W = (const float*)d_in[28];
    const float* fc1b = (const float*)d_in[29];
    const float* fc2W = (const float*)d_in[30];
    const float* fc2b = (const float*)d_in[31];

    float* ws    = (float*)d_ws;
    float* xa_m  = ws;                  // 131072
    float* xa_p  = xa_m + 131072;       // 262144
    float* xb_m  = xa_p + 262144;       // 131072
    float* xb_p  = xb_m + 131072;       // 262144
    float* Qm    = xb_p + 262144;       // 131072
    float* Kp    = Qm + 131072;         // 262144
    float* Vp    = Kp + 262144;         // 262144
    float* Qp    = Vp + 262144;         // 262144
    float* Km    = Qp + 262144;         // 131072
    float* Vm    = Km + 131072;         // 131072
    float* pool  = Vm + 131072;         // 4096
    float* cnt   = pool + 4096;         // 64
    float* partm = cnt + 64;            // 2048*4*4*20 = 655360
    float* partp = partm + 655360;      // 4096*4*2*20 = 655360
    int* deg     = (int*)(partp + 655360);  // 6144
    int* rowptr  = deg + N_TOT;             // 6145
    int* cursor  = rowptr + N_TOT + 1;      // 6144
    int* eidx    = cursor + N_TOT;          // 163840
    // H buffers reuse xa (dead after layer 2)
    float* Hm = xa_m;
    float* Hp = xa_p;

    k_node_lin<<<N_TOT / 4, 256, 0, stream>>>(mol_x, prot_x, nlmW, nlmb, nlpW, nlpb, xa_m, xa_p);

    hipMemsetAsync(deg, 0, N_TOT * sizeof(int), stream);
    k_deg<<<E_TOT / 256, 256, 0, stream>>>(mol_ei, prot_ei, deg);
    k_scan<<<1, 256, 0, stream>>>(deg, rowptr, cursor);
    k_fill<<<E_TOT / 256, 256, 0, stream>>>(mol_ei, prot_ei, cursor, eidx);

    // 3 GINE layers, ping-pong xa <-> xb; final result lands in xb
    k_gine<<<N_TOT / 4, 256, 0, stream>>>(xa_m, xa_p, xb_m, xb_p, mol_ea, prot_ea, mol_ei, prot_ei,
        elmW, elmb, elpW, elpb,
        mcW1, mcb1, mcW2, mcb2, pcW1, pcb1, pcW2, pcb2, rowptr, eidx);
    k_gine<<<N_TOT / 4, 256, 0, stream>>>(xb_m, xb_p, xa_m, xa_p, mol_ea, prot_ea, mol_ei, prot_ei,
        elmW, elmb, elpW, elpb,
        mcW1 + 4096, mcb1 + 64, mcW2 + 4096, mcb2 + 64,
        pcW1 + 4096, pcb1 + 64, pcW2 + 4096, pcb2 + 64, rowptr, eidx);
    k_gine<<<N_TOT / 4, 256, 0, stream>>>(xa_m, xa_p, xb_m, xb_p, mol_ea, prot_ea, mol_ei, prot_ei,
        elmW, elmb, elpW, elpb,
        mcW1 + 8192, mcb1 + 128, mcW2 + 8192, mcb2 + 128,
        pcW1 + 8192, pcb1 + 128, pcW2 + 8192, pcb2 + 128, rowptr, eidx);

    k_qkv<<<18432 / 4, 256, 0, stream>>>(xb_m, xb_p, mpW, mpb, pmW, pmb, Qm, Kp, Vp, Qp, Km, Vm);
    k_attn<<<(N_MOL / TQA) * CH_MOL + (N_PROT / TQA) * CH_PROT, 256, 0, stream>>>(
        Qm, Kp, Vp, Qp, Km, Vm, partm, partp);
    k_attn_merge<<<(N_MOL + N_PROT) * HEADS / 256, 256, 0, stream>>>(
        partm, partp, xb_m, xb_p, Hm, Hp);

    hipMemsetAsync(pool, 0, (size_t)(4096 + 64) * sizeof(float), stream);
    k_pool<<<N_TOT / 4, 256, 0, stream>>>(Hm, Hp, mol_b, prot_b, pool, cnt);
    k_final<<<BATCH, 64, 0, stream>>>(pool, cnt, fc1W, fc1b, fc2W, fc2b, (float*)d_out);
}